// Round 15
// baseline (94.605 us; speedup 1.0000x reference)
//
#include <hip/hip_runtime.h>
#include <hip/hip_bf16.h>
#include <cstdint>

#define NROWS 8192
#define NPER  4096
#define DIM   512
#define TEMP_INV 10.0f
#define FP8_SCALE 16.0f          // z scaled by 16 before e4m3 quantization
#define DOT_UNSCALE (1.0f / 256.0f)  // undo FP8_SCALE^2 on dot products
#define NT    128       // 8192 / 64 tile rows
#define NBLK  8256      // NT*(NT+1)/2 upper-tri 64x64 tiles (8256 % 8 == 0)
#define PAIR_OFF 64     // NPER / 64

typedef float f32x4 __attribute__((ext_vector_type(4)));
typedef long  lx2   __attribute__((ext_vector_type(2)));   // 16 B = 2 fp8 frags

// ---------------------------------------------------------------------------
// Kernel 1: L2-normalize rows of [view0; view1] -> z (fp8 e4m3, [8192][512]),
// scaled by FP8_SCALE. Also zeroes rowsum and out.
// ---------------------------------------------------------------------------
__global__ __launch_bounds__(256) void k_normalize(const float* __restrict__ v0,
                                                   const float* __restrict__ v1,
                                                   unsigned char* __restrict__ z,
                                                   float* __restrict__ rowsum,
                                                   float* __restrict__ out) {
  if (blockIdx.x < 32) rowsum[blockIdx.x * 256 + threadIdx.x] = 0.f;
  if (blockIdx.x == 0 && threadIdx.x == 0) out[0] = 0.f;
  const int wid  = (blockIdx.x * 256 + threadIdx.x) >> 6;  // row
  const int lane = threadIdx.x & 63;
  if (wid >= NROWS) return;
  const float* src = (wid < NPER) ? (v0 + (size_t)wid * DIM)
                                  : (v1 + (size_t)(wid - NPER) * DIM);
  float4 a = *(const float4*)(src + lane * 8);
  float4 b = *(const float4*)(src + lane * 8 + 4);
  float ss = a.x*a.x + a.y*a.y + a.z*a.z + a.w*a.w
           + b.x*b.x + b.y*b.y + b.z*b.z + b.w*b.w;
  #pragma unroll
  for (int m = 1; m < 64; m <<= 1) ss += __shfl_xor(ss, m);
  float inv = FP8_SCALE / fmaxf(sqrtf(ss), 1e-12f);
  // pack 8 fp8 e4m3 (hardware v_cvt_pk_fp8_f32, RNE, OCP format on gfx950)
  int w0 = __builtin_amdgcn_cvt_pk_fp8_f32(a.x * inv, a.y * inv, 0, false);
  w0     = __builtin_amdgcn_cvt_pk_fp8_f32(a.z * inv, a.w * inv, w0, true);
  int w1 = __builtin_amdgcn_cvt_pk_fp8_f32(b.x * inv, b.y * inv, 0, false);
  w1     = __builtin_amdgcn_cvt_pk_fp8_f32(b.z * inv, b.w * inv, w1, true);
  uint2 p; p.x = (unsigned)w0; p.y = (unsigned)w1;
  *(uint2*)(z + (size_t)wid * DIM + lane * 8) = p;
}

// ---------------------------------------------------------------------------
// Kernel 2 (R15): symmetric fused G = z z^T in FP8 e4m3 -- ZERO-SYNC design.
// One WAVE (64 threads) per 64x64 upper-tri tile; NO LDS, NO barriers,
// NO block-wide vmcnt drains. A and B fragments are loaded directly from
// global (z is 4 MB, L2-resident under the super-tile map) into registers
// with the R13-correctness-verified lane mapping, applied IDENTICALLY to
// both operands (row = base + idx*16 + r0, byte = k0 + g*16 + p*64; any
// within-k permutation cancels in the dot). The compiler software-pipelines
// the 64 wave-local loads with counted vmcnt -- 12-16 fully independent
// wave-streams per CU replace 12 barrier-locked ones. This is the clean
// test of the session-long finding that the synchronized drain (blocks add
// ~linearly: 1/2/3 blocks = 3.9/7.9/10.4 TB/s staging) is the limiter.
// Cost: 2x L2 traffic vs LDS sharing (528 MB, ~16 us at L2 ceiling) --
// cheap vs ~25 us of exposed drain. __launch_bounds__(64,4) caps regs at
// 128 (64 acc AGPR + ~60 arch) requesting 4 waves/SIMD.
// Tiling: 8256 upper-tri 64^2 tiles; supers of 16x16 tiles (1024^2 elems)
// keep per-XCD concurrent working set ~2-3 MB (L2-fit). T1 chunked XCD
// deal (8256 % 8 == 0). Positive-pair dots from tiles with bj-bi == 64.
// Epilogue: shfl-only reductions + direct atomicAdd (no LDS).
// ---------------------------------------------------------------------------
__global__ __launch_bounds__(64, 4) void k_gemm_sym(const unsigned char* __restrict__ z,
                                                    float* __restrict__ rowsum,
                                                    float* __restrict__ s) {
  const int lane = threadIdx.x;   // 0..63
  const int r0 = lane & 15;
  const int g  = lane >> 4;

  // T1 chunking: XCD x processes enumeration indices [x*1032, (x+1)*1032).
  const int orig = blockIdx.x;
  const int t = (orig & 7) * (NBLK / 8) + (orig >> 3);

  // ---- super-tile decode: supers of 16x16 tiles; start(a) = 2056a - 128a^2
  // (row a: 1 diag super of 136 tiles + (7-a) off supers of 256). ----
  int a = 0;
  while (a < 7 && (2056 * (a + 1) - 128 * (a + 1) * (a + 1)) <= t) ++a;
  int l = t - (2056 * a - 128 * a * a);
  int ri, rj, sj;
  if (l < 136) {                     // diagonal super (si == sj == a)
    sj = a;
    ri = 0;
    while (l >= 16 - ri) { l -= 16 - ri; ++ri; }
    rj = ri + l;
  } else {                           // off-diagonal supers, 256 tiles each
    l -= 136;
    sj = a + 1 + (l >> 8);
    const int ll = l & 255;
    ri = ll >> 4; rj = ll & 15;
  }
  const int bi = a * 16 + ri;
  const int bj = sj * 16 + rj;
  const int brow = bi * 64;
  const int bcol = bj * 64;
  const bool diag = (bi == bj);
  const bool pair = (bj - bi == PAIR_OFF);  // contains positive-pair diagonal

  f32x4 acc[4][4];
  const f32x4 zero = {0.f, 0.f, 0.f, 0.f};
  #pragma unroll
  for (int m = 0; m < 4; ++m)
    #pragma unroll
    for (int n = 0; n < 4; ++n) acc[m][n] = zero;

  // Per-lane base pointers: row (base + idx*16 + r0), byte (g*16 within the
  // 64-B k-segment). Per (idx,p,kt) the wave-load covers 16 rows x 64
  // contiguous B = 16 full lines (coalesced).
  const unsigned char* zA = z + (size_t)(brow + r0) * DIM + g * 16;
  const unsigned char* zB = z + (size_t)(bcol + r0) * DIM + g * 16;

  #pragma unroll
  for (int kt = 0; kt < 4; ++kt) {
    const int k0 = kt * 128;
    #pragma unroll
    for (int p = 0; p < 2; ++p) {
      const int kb = k0 + p * 64;
      lx2 aq[4], bq[4];
      #pragma unroll
      for (int m = 0; m < 4; ++m)
        aq[m] = *(const lx2*)(zA + (size_t)(m * 16) * DIM + kb);
      #pragma unroll
      for (int n = 0; n < 4; ++n)
        bq[n] = *(const lx2*)(zB + (size_t)(n * 16) * DIM + kb);
      #pragma unroll
      for (int m = 0; m < 4; ++m)
        #pragma unroll
        for (int n = 0; n < 4; ++n) {
          acc[m][n] = __builtin_amdgcn_mfma_f32_16x16x32_fp8_fp8(
              aq[m][0], bq[n][0], acc[m][n], 0, 0, 0);
          acc[m][n] = __builtin_amdgcn_mfma_f32_16x16x32_fp8_fp8(
              aq[m][1], bq[n][1], acc[m][n], 0, 0, 0);
        }
    }
  }

  // ---- epilogue: unscale; exp(10*g); row + col sums via shfl; pair dots ----
  float cs[4] = {0.f, 0.f, 0.f, 0.f};
  const float expc = TEMP_INV * DOT_UNSCALE;
  #pragma unroll
  for (int m = 0; m < 4; ++m) {
    #pragma unroll
    for (int j = 0; j < 4; ++j) {
      const int grow = brow + m * 16 + g * 4 + j;
      float v = 0.f;
      #pragma unroll
      for (int n = 0; n < 4; ++n) {
        const int gcol = bcol + n * 16 + r0;
        const float rawacc = acc[m][n][j];
        const float e = __expf(rawacc * expc);
        if (grow != gcol) { v += e; cs[n] += e; }   // skip self-similarity
        if (pair && (grow + NPER == gcol)) {        // positive-pair raw dot
          const float raw = rawacc * DOT_UNSCALE;
          s[grow] = raw;                            // dot(z_i, z_{i+NPER})
          s[gcol] = raw;                            // symmetric partner
        }
      }
      v += __shfl_xor(v, 1);
      v += __shfl_xor(v, 2);
      v += __shfl_xor(v, 4);
      v += __shfl_xor(v, 8);
      if (r0 == 0) atomicAdd(&rowsum[grow], v);     // 4 rows (g) per (m,j)
    }
  }
  if (!diag) {       // diag tiles: full tile already summed into rows above
    #pragma unroll
    for (int n = 0; n < 4; ++n) {
      float v = cs[n];
      v += __shfl_xor(v, 16);
      v += __shfl_xor(v, 32);
      if (g == 0) atomicAdd(&rowsum[bcol + n * 16 + r0], v);
    }
  }
}

// ---------------------------------------------------------------------------
// Kernel 3: loss = mean_i( log(denom_i) - s_i/T ), 32 blocks + atomicAdd
// (out zeroed in k_normalize; stream order guarantees visibility).
// ---------------------------------------------------------------------------
__global__ __launch_bounds__(256) void k_loss(const float* __restrict__ rowsum,
                                              const float* __restrict__ s,
                                              float* __restrict__ out) {
  __shared__ float red[4];
  const int i = blockIdx.x * 256 + threadIdx.x;
  float v = logf(rowsum[i]) - s[i] * TEMP_INV;
  #pragma unroll
  for (int m = 1; m < 64; m <<= 1) v += __shfl_xor(v, m);
  const int w = threadIdx.x >> 6;
  if ((threadIdx.x & 63) == 0) red[w] = v;
  __syncthreads();
  if (threadIdx.x == 0)
    atomicAdd(out, (red[0] + red[1] + red[2] + red[3]) * (1.0f / (float)NROWS));
}

extern "C" void kernel_launch(void* const* d_in, const int* in_sizes, int n_in,
                              void* d_out, int out_size, void* d_ws, size_t ws_size,
                              hipStream_t stream) {
  const float* v0 = (const float*)d_in[0];
  const float* v1 = (const float*)d_in[1];
  float* out = (float*)d_out;

  unsigned char* z = (unsigned char*)d_ws;                      // 8192*512 B
  float* rowsum = (float*)((char*)d_ws + (size_t)NROWS * DIM);
  float* s      = rowsum + NROWS;

  k_normalize<<<NROWS / 4, 256, 0, stream>>>(v0, v1, z, rowsum, out);
  k_gemm_sym<<<NBLK, 64, 0, stream>>>(z, rowsum, s);
  k_loss<<<NROWS / 256, 256, 0, stream>>>(rowsum, s, out);
}

// Round 16
// 52.551 us; speedup vs baseline: 1.8003x; 1.8003x over previous
//
#include <hip/hip_runtime.h>
#include <hip/hip_bf16.h>
#include <cstdint>

#define NROWS 8192
#define NPER  4096
#define DIM   512
#define TEMP_INV 10.0f
#define FP8_SCALE 16.0f          // z scaled by 16 before e4m3 quantization
#define DOT_UNSCALE (1.0f / 256.0f)  // undo FP8_SCALE^2 on dot products
#define NB    64        // 8192 / 128 row-blocks
#define NBLK  2080      // NB*(NB+1)/2 upper-tri 128x128 tiles
#define PAIR_OFF 32     // NPER / 128

typedef float f32x4 __attribute__((ext_vector_type(4)));
typedef long  lx2   __attribute__((ext_vector_type(2)));   // 16 B = 2 fp8 frags

// ---------------------------------------------------------------------------
// Kernel 1: L2-normalize rows of [view0; view1] -> z (fp8 e4m3, [8192][512]),
// scaled by FP8_SCALE. Also zeroes rowsum and out.
// ---------------------------------------------------------------------------
__global__ __launch_bounds__(256) void k_normalize(const float* __restrict__ v0,
                                                   const float* __restrict__ v1,
                                                   unsigned char* __restrict__ z,
                                                   float* __restrict__ rowsum,
                                                   float* __restrict__ out) {
  if (blockIdx.x < 32) rowsum[blockIdx.x * 256 + threadIdx.x] = 0.f;
  if (blockIdx.x == 0 && threadIdx.x == 0) out[0] = 0.f;
  const int wid  = (blockIdx.x * 256 + threadIdx.x) >> 6;  // row
  const int lane = threadIdx.x & 63;
  if (wid >= NROWS) return;
  const float* src = (wid < NPER) ? (v0 + (size_t)wid * DIM)
                                  : (v1 + (size_t)(wid - NPER) * DIM);
  float4 a = *(const float4*)(src + lane * 8);
  float4 b = *(const float4*)(src + lane * 8 + 4);
  float ss = a.x*a.x + a.y*a.y + a.z*a.z + a.w*a.w
           + b.x*b.x + b.y*b.y + b.z*b.z + b.w*b.w;
  #pragma unroll
  for (int m = 1; m < 64; m <<= 1) ss += __shfl_xor(ss, m);
  float inv = FP8_SCALE / fmaxf(sqrtf(ss), 1e-12f);
  // pack 8 fp8 e4m3 (hardware v_cvt_pk_fp8_f32, RNE, OCP format on gfx950)
  int w0 = __builtin_amdgcn_cvt_pk_fp8_f32(a.x * inv, a.y * inv, 0, false);
  w0     = __builtin_amdgcn_cvt_pk_fp8_f32(a.z * inv, a.w * inv, w0, true);
  int w1 = __builtin_amdgcn_cvt_pk_fp8_f32(b.x * inv, b.y * inv, 0, false);
  w1     = __builtin_amdgcn_cvt_pk_fp8_f32(b.z * inv, b.w * inv, w1, true);
  uint2 p; p.x = (unsigned)w0; p.y = (unsigned)w1;
  *(uint2*)(z + (size_t)wid * DIM + lane * 8) = p;
}

// ---------------------------------------------------------------------------
// Kernel 2 (R16): symmetric fused G = z z^T, FP8 e4m3, 128x128 upper-tri
// tiles, 4 waves (2x2), per-wave 64x64 (acc[4][4] = 64 AGPR), 3 blocks/CU.
// R11's 3-slab ONE-barrier counted-vmcnt pipeline, retried with a
// conflict-free-by-construction read pattern (R11's 12.8M conflict cycles
// = 38% of its runtime were the whole regression; structure untested).
// BK=64: slab = A 8 KB + B 8 KB; 3 slabs = 48 KB -> 3 blocks/CU. 8 iters.
//   iter kt: vmcnt(4) [certify S(kt); S(kt+1) stays in flight; vmcnt(0)
//            only at kt=7] -> s_barrier -> stage S(kt+2) into slab
//            (kt+2)%3 == (kt-1)%3 (its readers just certified by THIS
//            barrier: every wave consumed its iter-(kt-1) ds_reads before
//            reaching it) -> 8 ds_read_b128 + 32 MFMA -> lgkmcnt(0).
// Read pattern: lane reads 16 B covering BOTH kk frags (k-relabel: lane g
// owns bytes g*16..+15 of each 64-B row; A and B identical -> dot
// unchanged). Phys slot = (g + (r0>>1)) & 3. Lanes 0-7 hit 16-B bank
// groups {0,4,1,5,2,6,3,7} (all distinct); lanes 8-15 repeat at different
// addrs (2-way = free) -- same structural property as the R4/R10 patterns
// that measured 0 conflicts. Stage: linear LDS dest, global source slot
// ((l&3) - (l>>3)) & 3 (rule #21); 4 lanes/row cover a full 64-B line.
// R8 super-tile locality map kept. Pair dots from tiles with bj-bi == 32.
// ---------------------------------------------------------------------------
__global__ __launch_bounds__(256, 3) void k_gemm_sym(const unsigned char* __restrict__ z,
                                                     float* __restrict__ rowsum,
                                                     float* __restrict__ s) {
  __shared__ __align__(16) unsigned char As[3][128 * 64];   // 3 x 8 KB
  __shared__ __align__(16) unsigned char Bs[3][128 * 64];   // 3 x 8 KB

  const int tid  = threadIdx.x;
  const int lane = tid & 63;
  const int w    = tid >> 6;      // 0..3
  const int wr   = w >> 1;        // 0..1 (row half)
  const int wc   = w & 1;         // 0..1 (col half)

  // T1 chunking: XCD x processes enumeration indices [x*260, (x+1)*260).
  const int orig = blockIdx.x;
  const int t = (orig & 7) * (NBLK / 8) + (orig >> 3);

  // ---- super-tile decode (R8) ----
  int a = 0;
  while (a < 7 && 484 * (a + 1) - 32 * (a + 1) * a <= t) ++a;
  int l = t - (484 * a - 32 * a * (a - 1));
  int ri, rj, sj;
  if (l < 36) {                      // diagonal super (si == sj == a)
    sj = a;
    ri = 0;
    while (l >= 8 - ri) { l -= 8 - ri; ++ri; }
    rj = ri + l;
  } else {                           // off-diagonal supers, 64 tiles each
    l -= 36;
    sj = a + 1 + (l >> 6);
    const int ll = l & 63;
    ri = ll >> 3; rj = ll & 7;
  }
  const int bi = a * 8 + ri;
  const int bj = sj * 8 + rj;
  const int brow = bi * 128;
  const int bcol = bj * 128;
  const bool diag = (bi == bj);
  const bool pair = (bj - bi == PAIR_OFF);  // contains positive-pair diagonal

  f32x4 acc[4][4];
  const f32x4 zero = {0.f, 0.f, 0.f, 0.f};
  #pragma unroll
  for (int m = 0; m < 4; ++m)
    #pragma unroll
    for (int n = 0; n < 4; ++n) acc[m][n] = zero;

  // Stage one BK=64 slab (A 8 KB + B 8 KB). 4 gload_lds/thread (2 A + 2 B).
  // Chunk = 16 rows x 64 B = 1 KB. Lane l -> row l>>2, phys slot l&3;
  // global source slot sL = ((l&3) - (l>>3)) & 3 so the linear LDS write
  // realizes phys slot = (sL + (row>>1)) & 3 (rule #21).
  const int srow4 = lane >> 2;                          // 0..15 row in chunk
  const int skof4 = 16 * (((lane & 3) - (lane >> 3)) & 3);  // pre-swz bytes
  auto stage = [&](int slab, int kt) {
    const int k0 = kt * 64;
    #pragma unroll
    for (int i = 0; i < 2; ++i) {
      const int c = w * 2 + i;                          // chunk 0..7
      const int row_in = c * 16 + srow4;
      const unsigned char* ga = z + (size_t)(brow + row_in) * DIM + k0 + skof4;
      const unsigned char* gb = z + (size_t)(bcol + row_in) * DIM + k0 + skof4;
      __builtin_amdgcn_global_load_lds(
          (const __attribute__((address_space(1))) void*)ga,
          (__attribute__((address_space(3))) void*)(&As[slab][c * 1024]), 16, 0, 0);
      __builtin_amdgcn_global_load_lds(
          (const __attribute__((address_space(1))) void*)gb,
          (__attribute__((address_space(3))) void*)(&Bs[slab][c * 1024]), 16, 0, 0);
    }
  };

  // prologue: S0, S1 in flight (8 loads/thread)
  stage(0, 0);
  stage(1, 1);

  const int r0 = lane & 15;
  const int g  = lane >> 4;
  const int ps = ((g + (r0 >> 1)) & 3) * 16;    // phys slot byte offset

  for (int kt = 0; kt < 8; ++kt) {
    const int cur = kt % 3;
    // certify S(kt): per-thread outstanding = {S(kt):4, S(kt+1):4} ->
    // vmcnt(4) drains exactly S(kt); never 0 until the last iter (T4).
    if (kt < 7) asm volatile("s_waitcnt vmcnt(4)" ::: "memory");
    else        asm volatile("s_waitcnt vmcnt(0)" ::: "memory");
    __builtin_amdgcn_s_barrier();               // single barrier per iter
    __builtin_amdgcn_sched_barrier(0);
    if (kt < 6) stage((kt + 2) % 3, kt + 2);    // lead-2; target slab's
                                                // readers certified above

    const char* Ab = (const char*)&As[cur][0] + (size_t)(wr * 64 + r0) * 64 + ps;
    const char* Bb = (const char*)&Bs[cur][0] + (size_t)(wc * 64 + r0) * 64 + ps;
    lx2 bfrag[4];
    #pragma unroll
    for (int n = 0; n < 4; ++n)
      bfrag[n] = *(const lx2*)(Bb + n * (16 * 64));
    #pragma unroll
    for (int m = 0; m < 4; ++m) {
      lx2 afrag = *(const lx2*)(Ab + m * (16 * 64));
      #pragma unroll
      for (int n = 0; n < 4; ++n) {
        acc[m][n] = __builtin_amdgcn_mfma_f32_16x16x32_fp8_fp8(
            afrag[0], bfrag[n][0], acc[m][n], 0, 0, 0);
        acc[m][n] = __builtin_amdgcn_mfma_f32_16x16x32_fp8_fp8(
            afrag[1], bfrag[n][1], acc[m][n], 0, 0, 0);
      }
    }
    // wave's reads of slab cur complete before it reaches the next head
    // barrier (which certifies cur free for the overwrite at iter kt+1).
    asm volatile("s_waitcnt lgkmcnt(0)" ::: "memory");
    __builtin_amdgcn_sched_barrier(0);
  }

  // ---- epilogue: unscale; exp(10*g); row + col sums; pair dots ----
  // racc/cacc alias As[0] (2 KB): slab 0 last read at iter 6; those reads
  // were certified complete for ALL waves at iter 7's head barrier, and
  // iter 7 reads slab 1 only -> disjoint.
  float (*racc)[128] = (float (*)[128])As;        // [2][128]
  float (*cacc)[128] = ((float (*)[128])As) + 2;  // [2][128]

  float cs[4] = {0.f, 0.f, 0.f, 0.f};
  const int grow0 = brow + wr * 64;
  const int gcol0 = bcol + wc * 64;
  const float expc = TEMP_INV * DOT_UNSCALE;
  #pragma unroll
  for (int m = 0; m < 4; ++m) {
    #pragma unroll
    for (int j = 0; j < 4; ++j) {
      const int grow = grow0 + m * 16 + g * 4 + j;
      float v = 0.f;
      #pragma unroll
      for (int n = 0; n < 4; ++n) {
        const int gcol = gcol0 + n * 16 + r0;
        const float rawacc = acc[m][n][j];
        const float e = __expf(rawacc * expc);
        if (grow != gcol) { v += e; cs[n] += e; }   // skip self-similarity
        if (pair && (grow + NPER == gcol)) {        // positive-pair raw dot
          const float raw = rawacc * DOT_UNSCALE;
          s[grow] = raw;                            // dot(z_i, z_{i+NPER})
          s[gcol] = raw;                            // symmetric partner
        }
      }
      v += __shfl_xor(v, 1);
      v += __shfl_xor(v, 2);
      v += __shfl_xor(v, 4);
      v += __shfl_xor(v, 8);
      if (r0 == 0) racc[wc][wr * 64 + m * 16 + g * 4 + j] = v;
    }
  }
  #pragma unroll
  for (int n = 0; n < 4; ++n) {
    float v = cs[n];
    v += __shfl_xor(v, 16);
    v += __shfl_xor(v, 32);
    if (lane < 16) cacc[wr][wc * 64 + n * 16 + lane] = v;
  }
  __syncthreads();
  if (tid < 128) {
    atomicAdd(&rowsum[brow + tid], racc[0][tid] + racc[1][tid]);
  } else if (!diag) {
    const int i = tid - 128;
    atomicAdd(&rowsum[bcol + i], cacc[0][i] + cacc[1][i]);
  }
}

// ---------------------------------------------------------------------------
// Kernel 3: loss = mean_i( log(denom_i) - s_i/T ), 32 blocks + atomicAdd
// (out zeroed in k_normalize; stream order guarantees visibility).
// ---------------------------------------------------------------------------
__global__ __launch_bounds__(256) void k_loss(const float* __restrict__ rowsum,
                                              const float* __restrict__ s,
                                              float* __restrict__ out) {
  __shared__ float red[4];
  const int i = blockIdx.x * 256 + threadIdx.x;
  float v = logf(rowsum[i]) - s[i] * TEMP_INV;
  #pragma unroll
  for (int m = 1; m < 64; m <<= 1) v += __shfl_xor(v, m);
  const int w = threadIdx.x >> 6;
  if ((threadIdx.x & 63) == 0) red[w] = v;
  __syncthreads();
  if (threadIdx.x == 0)
    atomicAdd(out, (red[0] + red[1] + red[2] + red[3]) * (1.0f / (float)NROWS));
}

extern "C" void kernel_launch(void* const* d_in, const int* in_sizes, int n_in,
                              void* d_out, int out_size, void* d_ws, size_t ws_size,
                              hipStream_t stream) {
  const float* v0 = (const float*)d_in[0];
  const float* v1 = (const float*)d_in[1];
  float* out = (float*)d_out;

  unsigned char* z = (unsigned char*)d_ws;                      // 8192*512 B
  float* rowsum = (float*)((char*)d_ws + (size_t)NROWS * DIM);
  float* s      = rowsum + NROWS;

  k_normalize<<<NROWS / 4, 256, 0, stream>>>(v0, v1, z, rowsum, out);
  k_gemm_sym<<<NBLK, 256, 0, stream>>>(z, rowsum, s);
  k_loss<<<NROWS / 256, 256, 0, stream>>>(rowsum, s, out);
}

// Round 17
// 49.288 us; speedup vs baseline: 1.9194x; 1.0662x over previous
//
#include <hip/hip_runtime.h>
#include <hip/hip_bf16.h>
#include <cstdint>

#define NROWS 8192
#define NPER  4096
#define DIM   512
#define TEMP_INV 10.0f
#define FP8_SCALE 16.0f          // z scaled by 16 before e4m3 quantization
#define DOT_UNSCALE (1.0f / 256.0f)  // undo FP8_SCALE^2 on dot products
#define NB    64        // 8192 / 128 row-blocks
#define NBLK  2080      // NB*(NB+1)/2 upper-tri 128x128 tiles
#define PAIR_OFF 32     // NPER / 128

typedef float f32x4 __attribute__((ext_vector_type(4)));
typedef long  lx2   __attribute__((ext_vector_type(2)));   // 16 B = 2 fp8 frags

// ---------------------------------------------------------------------------
// Kernel 1: L2-normalize rows of [view0; view1] -> z (fp8 e4m3, [8192][512]),
// scaled by FP8_SCALE (moves typical |z|~0.04 out of the subnormal zone;
// e4m3 max 448 >> 16). Also zeroes rowsum and out.
// ---------------------------------------------------------------------------
__global__ __launch_bounds__(256) void k_normalize(const float* __restrict__ v0,
                                                   const float* __restrict__ v1,
                                                   unsigned char* __restrict__ z,
                                                   float* __restrict__ rowsum,
                                                   float* __restrict__ out) {
  if (blockIdx.x < 32) rowsum[blockIdx.x * 256 + threadIdx.x] = 0.f;
  if (blockIdx.x == 0 && threadIdx.x == 0) out[0] = 0.f;
  const int wid  = (blockIdx.x * 256 + threadIdx.x) >> 6;  // row
  const int lane = threadIdx.x & 63;
  if (wid >= NROWS) return;
  const float* src = (wid < NPER) ? (v0 + (size_t)wid * DIM)
                                  : (v1 + (size_t)(wid - NPER) * DIM);
  float4 a = *(const float4*)(src + lane * 8);
  float4 b = *(const float4*)(src + lane * 8 + 4);
  float ss = a.x*a.x + a.y*a.y + a.z*a.z + a.w*a.w
           + b.x*b.x + b.y*b.y + b.z*b.z + b.w*b.w;
  #pragma unroll
  for (int m = 1; m < 64; m <<= 1) ss += __shfl_xor(ss, m);
  float inv = FP8_SCALE / fmaxf(sqrtf(ss), 1e-12f);
  // pack 8 fp8 e4m3 (hardware v_cvt_pk_fp8_f32, RNE, OCP format on gfx950)
  int w0 = __builtin_amdgcn_cvt_pk_fp8_f32(a.x * inv, a.y * inv, 0, false);
  w0     = __builtin_amdgcn_cvt_pk_fp8_f32(a.z * inv, a.w * inv, w0, true);
  int w1 = __builtin_amdgcn_cvt_pk_fp8_f32(b.x * inv, b.y * inv, 0, false);
  w1     = __builtin_amdgcn_cvt_pk_fp8_f32(b.z * inv, b.w * inv, w1, true);
  uint2 p; p.x = (unsigned)w0; p.y = (unsigned)w1;
  *(uint2*)(z + (size_t)wid * DIM + lane * 8) = p;
}

// ---------------------------------------------------------------------------
// Kernel 2: symmetric fused G = z z^T in FP8 e4m3 (mfma_f32_16x16x32_fp8_fp8,
// bf16-rate, half the bytes). 128x128 upper-tri tiles, 4 waves (2x2),
// per-wave 64x64 (acc[4][4] = 64 AGPR), BK=128 SINGLE-buffered (32 KB LDS,
// 3 blocks/CU = the verified residency ceiling, 4 K-iterations).
// FINAL (R17 = R10 verbatim, the session's best verified kernel).
// Structure inventory tested and beaten by this simple drain loop:
// multi-phase interleave (R1/R3), deeper prefetch (R6/R11/R16), rect/256^2
// tiles (R0/R7), 4 blocks/CU (R5/R12 - never granted), zero-sync 1-wave
// (R15), B-direct-from-L2 (R13), pitch padding (R14). Remaining limiter:
// fp8 L2 request service (~0.67 16-B req/cyc/CU vs bf16's 1.06) under the
// 3-block residency cap -- no falsifiable theory survived for the gap.
// Conflict-free LDS reads: 16 B per lane (ds_read_b128) at phys 16B-slot
// (2g+p)^(r0&7), row stride 128 B (0 conflicts measured). Each b128 holds
// TWO 8-B MFMA fragments; k-regrouping applied identically to A and B so
// the dot product is unchanged. Staging pre-swizzles the global source
// (rule #21). R8 super-tile locality map (FETCH 53->21->10 MB over the
// session). Positive-pair dots harvested from tiles with bj-bi == 32.
// ---------------------------------------------------------------------------
__global__ __launch_bounds__(256, 3) void k_gemm_sym(const unsigned char* __restrict__ z,
                                                     float* __restrict__ rowsum,
                                                     float* __restrict__ s) {
  __shared__ __align__(16) unsigned char As[128 * 128];   // 16 KB
  __shared__ __align__(16) unsigned char Bs[128 * 128];   // 16 KB

  const int tid  = threadIdx.x;
  const int lane = tid & 63;
  const int w    = tid >> 6;      // 0..3
  const int wr   = w >> 1;        // 0..1 (row half)
  const int wc   = w & 1;         // 0..1 (col half)

  // T1 chunking: XCD x processes enumeration indices [x*260, (x+1)*260).
  const int orig = blockIdx.x;
  const int t = (orig & 7) * (NBLK / 8) + (orig >> 3);

  // ---- super-tile decode (R8) ----
  int a = 0;
  while (a < 7 && 484 * (a + 1) - 32 * (a + 1) * a <= t) ++a;
  int l = t - (484 * a - 32 * a * (a - 1));
  int ri, rj, sj;
  if (l < 36) {                      // diagonal super (si == sj == a)
    sj = a;
    ri = 0;
    while (l >= 8 - ri) { l -= 8 - ri; ++ri; }
    rj = ri + l;
  } else {                           // off-diagonal supers, 64 tiles each
    l -= 36;
    sj = a + 1 + (l >> 6);
    const int ll = l & 63;
    ri = ll >> 3; rj = ll & 7;
  }
  const int bi = a * 8 + ri;
  const int bj = sj * 8 + rj;
  const int brow = bi * 128;
  const int bcol = bj * 128;
  const bool diag = (bi == bj);
  const bool pair = (bj - bi == PAIR_OFF);  // contains positive-pair diagonal

  f32x4 acc[4][4];
  const f32x4 zero = {0.f, 0.f, 0.f, 0.f};
  #pragma unroll
  for (int m = 0; m < 4; ++m)
    #pragma unroll
    for (int n = 0; n < 4; ++n) acc[m][n] = zero;

  // stage one BK=128 K-slab (A and B tiles, 16 KB each). 8 global_load_lds
  // per thread (4 A + 4 B). Chunk = 8 rows x 128 B = 1 KB (one wave-load).
  // LDS dest linear; global source pre-swizzled: 16B-slot ^= (row & 7).
  const int srow = (lane >> 3);                  // 0..7 row within chunk
  const int skof = 16 * ((lane & 7) ^ srow);     // pre-swizzled k-offset (bytes)
  auto stage = [&](int k0) {
    #pragma unroll
    for (int i = 0; i < 4; ++i) {
      const int c = w * 4 + i;                   // chunk 0..15 (8 rows each)
      const int row_in = c * 8 + srow;
      const unsigned char* ga = z + (size_t)(brow + row_in) * DIM + k0 + skof;
      const unsigned char* gb = z + (size_t)(bcol + row_in) * DIM + k0 + skof;
      __builtin_amdgcn_global_load_lds(
          (const __attribute__((address_space(1))) void*)ga,
          (__attribute__((address_space(3))) void*)(&As[c * 1024]), 16, 0, 0);
      __builtin_amdgcn_global_load_lds(
          (const __attribute__((address_space(1))) void*)gb,
          (__attribute__((address_space(3))) void*)(&Bs[c * 1024]), 16, 0, 0);
    }
  };

  const int r0 = lane & 15;
  const int g  = lane >> 4;

  for (int kt = 0; kt < 4; ++kt) {
    stage(kt * 128);
    // single buffer: own loads drained, then all waves' loads visible.
    asm volatile("s_waitcnt vmcnt(0)" ::: "memory");
    __builtin_amdgcn_s_barrier();

    const char* Ab = (const char*)&As[0] + (size_t)(wr * 64 + r0) * 128;
    const char* Bb = (const char*)&Bs[0] + (size_t)(wc * 64 + r0) * 128;
    #pragma unroll
    for (int p = 0; p < 2; ++p) {
      // 16-B read at phys slot (2g+p)^(r0&7): verified 0-conflict pattern.
      const int cb = (((2 * g + p) ^ (r0 & 7)) << 4);
      lx2 bfrag[4];
      #pragma unroll
      for (int n = 0; n < 4; ++n)
        bfrag[n] = *(const lx2*)(Bb + n * (16 * 128) + cb);
      #pragma unroll
      for (int m = 0; m < 4; ++m) {
        lx2 afrag = *(const lx2*)(Ab + m * (16 * 128) + cb);
        #pragma unroll
        for (int n = 0; n < 4; ++n) {
          acc[m][n] = __builtin_amdgcn_mfma_f32_16x16x32_fp8_fp8(
              afrag[0], bfrag[n][0], acc[m][n], 0, 0, 0);
          acc[m][n] = __builtin_amdgcn_mfma_f32_16x16x32_fp8_fp8(
              afrag[1], bfrag[n][1], acc[m][n], 0, 0, 0);
        }
      }
    }
    // all LDS reads done in this wave, sync all waves -> safe to overwrite.
    asm volatile("s_waitcnt lgkmcnt(0)" ::: "memory");
    __builtin_amdgcn_sched_barrier(0);
    __builtin_amdgcn_s_barrier();
  }

  // ---- epilogue: unscale; exp(10*g); row + col sums; pair dots ----
  // smem reduction arrays aliased into As (all LDS reads drained above).
  float (*racc)[128] = (float (*)[128])As;        // [2][128]
  float (*cacc)[128] = ((float (*)[128])As) + 2;  // [2][128]

  float cs[4] = {0.f, 0.f, 0.f, 0.f};
  const int grow0 = brow + wr * 64;
  const int gcol0 = bcol + wc * 64;
  const float expc = TEMP_INV * DOT_UNSCALE;
  #pragma unroll
  for (int m = 0; m < 4; ++m) {
    #pragma unroll
    for (int j = 0; j < 4; ++j) {
      const int grow = grow0 + m * 16 + g * 4 + j;
      float v = 0.f;
      #pragma unroll
      for (int n = 0; n < 4; ++n) {
        const int gcol = gcol0 + n * 16 + r0;
        const float rawacc = acc[m][n][j];
        const float e = __expf(rawacc * expc);
        if (grow != gcol) { v += e; cs[n] += e; }   // skip self-similarity
        if (pair && (grow + NPER == gcol)) {        // positive-pair raw dot
          const float raw = rawacc * DOT_UNSCALE;
          s[grow] = raw;                            // dot(z_i, z_{i+NPER})
          s[gcol] = raw;                            // symmetric partner
        }
      }
      v += __shfl_xor(v, 1);
      v += __shfl_xor(v, 2);
      v += __shfl_xor(v, 4);
      v += __shfl_xor(v, 8);
      if (r0 == 0) racc[wc][wr * 64 + m * 16 + g * 4 + j] = v;
    }
  }
  #pragma unroll
  for (int n = 0; n < 4; ++n) {
    float v = cs[n];
    v += __shfl_xor(v, 16);
    v += __shfl_xor(v, 32);
    if (lane < 16) cacc[wr][wc * 64 + n * 16 + lane] = v;
  }
  __syncthreads();
  if (tid < 128) {
    atomicAdd(&rowsum[brow + tid], racc[0][tid] + racc[1][tid]);
  } else if (!diag) {
    const int i = tid - 128;
    atomicAdd(&rowsum[bcol + i], cacc[0][i] + cacc[1][i]);
  }
}

// ---------------------------------------------------------------------------
// Kernel 3: loss = mean_i( log(denom_i) - s_i/T ), 32 blocks + atomicAdd
// (out zeroed in k_normalize; stream order guarantees visibility).
// ---------------------------------------------------------------------------
__global__ __launch_bounds__(256) void k_loss(const float* __restrict__ rowsum,
                                              const float* __restrict__ s,
                                              float* __restrict__ out) {
  __shared__ float red[4];
  const int i = blockIdx.x * 256 + threadIdx.x;
  float v = logf(rowsum[i]) - s[i] * TEMP_INV;
  #pragma unroll
  for (int m = 1; m < 64; m <<= 1) v += __shfl_xor(v, m);
  const int w = threadIdx.x >> 6;
  if ((threadIdx.x & 63) == 0) red[w] = v;
  __syncthreads();
  if (threadIdx.x == 0)
    atomicAdd(out, (red[0] + red[1] + red[2] + red[3]) * (1.0f / (float)NROWS));
}

extern "C" void kernel_launch(void* const* d_in, const int* in_sizes, int n_in,
                              void* d_out, int out_size, void* d_ws, size_t ws_size,
                              hipStream_t stream) {
  const float* v0 = (const float*)d_in[0];
  const float* v1 = (const float*)d_in[1];
  float* out = (float*)d_out;

  unsigned char* z = (unsigned char*)d_ws;                      // 8192*512 B
  float* rowsum = (float*)((char*)d_ws + (size_t)NROWS * DIM);
  float* s      = rowsum + NROWS;

  k_normalize<<<NROWS / 4, 256, 0, stream>>>(v0, v1, z, rowsum, out);
  k_gemm_sym<<<NBLK, 256, 0, stream>>>(z, rowsum, s);
  k_loss<<<NROWS / 256, 256, 0, stream>>>(rowsum, s, out);
}